// Round 14
// baseline (431.837 us; speedup 1.0000x reference)
//
#include <hip/hip_runtime.h>

#define N_NODES 50000
#define N_EDGES 800000
#define IN_DIM 768
#define HIDDEN 256
#define N_CLASSES 10
#define N_GRAPHS 128

typedef __attribute__((ext_vector_type(8))) short bf16x8;
typedef __attribute__((ext_vector_type(4))) float f32x4;
typedef __attribute__((ext_vector_type(8))) unsigned short u16x8;

__device__ __forceinline__ float bf2f(unsigned short u) {
    union { unsigned int i; float f; } c; c.i = ((unsigned int)u) << 16; return c.f;
}
__device__ __forceinline__ unsigned short f2bf(float f) {
    unsigned int x = __float_as_uint(f);
    return (unsigned short)((x + 0x7fffu + ((x >> 16) & 1u)) >> 16);  // RNE
}

// async global->LDS, 16B per lane; LDS dest = uniform base + lane*16
__device__ __forceinline__ void gload16(const void* g, void* l) {
    __builtin_amdgcn_global_load_lds((const __attribute__((address_space(1))) void*)g,
                                     (__attribute__((address_space(3))) void*)l, 16, 0, 0);
}

// ---------------- CSR build ----------------
__global__ void zero_int(int* p, int n) {
    int i = blockIdx.x * blockDim.x + threadIdx.x;
    if (i < n) p[i] = 0;
}

__global__ void zero_f32(float* p, int n) {
    int i = blockIdx.x * blockDim.x + threadIdx.x;
    if (i < n) p[i] = 0.f;
}

__global__ void hist_dst(const int* __restrict__ dst, int* __restrict__ cnt) {
    int e = blockIdx.x * blockDim.x + threadIdx.x;
    if (e < N_EDGES) atomicAdd(&cnt[dst[e]], 1);
}

// single-block exclusive scan (shfl-based) + fused dinv = rsqrt(1+cnt)
__global__ __launch_bounds__(1024) void scan_kernel(const int* __restrict__ cnt,
                                                    int* __restrict__ rowstart,
                                                    int* __restrict__ cursor,
                                                    float* __restrict__ dinv) {
    __shared__ int wsum[16];
    __shared__ int chunk_carry;
    const int tid = threadIdx.x, lane = tid & 63, wid = tid >> 6;
    if (tid == 0) chunk_carry = 0;
    __syncthreads();
    for (int base = 0; base < N_NODES; base += 1024) {
        int i = base + tid;
        int v = (i < N_NODES) ? cnt[i] : 0;
        if (i < N_NODES) dinv[i] = rsqrtf(1.0f + (float)v);
        int s = v;
#pragma unroll
        for (int d = 1; d < 64; d <<= 1) { int t = __shfl_up(s, d); if (lane >= d) s += t; }
        if (lane == 63) wsum[wid] = s;
        __syncthreads();
        if (tid < 16) {
            int ww = wsum[tid];
#pragma unroll
            for (int d = 1; d < 16; d <<= 1) { int t = __shfl_up(ww, d); if (tid >= d) ww += t; }
            wsum[tid] = ww;
        }
        __syncthreads();
        int wpre = (wid == 0) ? 0 : wsum[wid - 1];
        int excl = chunk_carry + wpre + s - v;
        if (i < N_NODES) { rowstart[i] = excl; cursor[i] = excl; }
        int total = wsum[15];
        __syncthreads();
        if (tid == 0) chunk_carry += total;
        __syncthreads();
    }
    if (threadIdx.x == 0) rowstart[N_NODES] = chunk_carry;
}

__global__ void scatter_edges(const int* __restrict__ src, const int* __restrict__ dst,
                              int* __restrict__ cursor, int* __restrict__ col) {
    int e = blockIdx.x * blockDim.x + threadIdx.x;
    if (e >= N_EDGES) return;
    int d = dst[e];
    int pos = atomicAdd(&cursor[d], 1);
    col[pos] = src[e];
}

// ---------------- W [K][256] fp32 -> WT [256][K] bf16, LDS-tiled ----------------
__global__ __launch_bounds__(256) void transpose_w_bf16(const float* __restrict__ W,
                                                        unsigned short* __restrict__ WT, int K) {
    __shared__ float t[32][33];
    int tx = threadIdx.x & 31, ty = threadIdx.x >> 5;  // 8 row-groups
    int k0 = blockIdx.x * 32, n0 = blockIdx.y * 32;
#pragma unroll
    for (int i = 0; i < 4; ++i) {
        int k = k0 + ty + i * 8;
        t[ty + i * 8][tx] = W[(size_t)k * 256 + n0 + tx];
    }
    __syncthreads();
#pragma unroll
    for (int i = 0; i < 4; ++i) {
        int n = n0 + ty + i * 8;
        WT[(size_t)n * K + k0 + tx] = f2bf(t[tx][ty + i * 8]);
    }
}

// ---------------- MFMA GEMM: C[M,256](bf16) = A[M,K] * BT[256,K]^T ----
// tile 32x256, BK=64; 4 waves split N (wave w owns cols [64w,64w+64)), all share
// the 32 A-rows. grid ceil(M/32) ~ 1563 -> ~6 blocks/CU demanded, LDS 36KB ->
// 4 blocks/CU resident: inter-block overlap hides the per-step staging drain.
// CVT=false: A bf16 staged via global_load_lds (linear dest, pre-swizzled src).
// CVT=true:  A f32, reg-staged + converted + swizzled ds_write.
// LDS slot [r][g] holds source granule g^(r&7); reads apply the same XOR.
template <int K, bool CVT>
__global__ __launch_bounds__(256, 4) void gemm_mfma(const void* __restrict__ Av,
                                                    const unsigned short* __restrict__ BT,
                                                    unsigned short* __restrict__ C, int M) {
    __shared__ uint4 sm[2304];  // 36 KB: As [32][8] granules (4 KB), Bs [256][8] (32 KB)
    uint4* As = sm;
    uint4* Bs = sm + 256;
    const int tid = threadIdx.x;
    const int lane = tid & 63, w = tid >> 6;
    const int lr = lane & 15, kg = lane >> 4;
    const int bm = blockIdx.x * 32;

    f32x4 acc[2][4] = {};

    for (int k0 = 0; k0 < K; k0 += 64) {
        // stage A: 256 granules (32 rows x 8)
        if constexpr (CVT) {
            const float* Af = (const float*)Av;
            int r = tid >> 3, g = tid & 7;
            int gs = g ^ (r & 7);
            int rg = bm + r; rg = rg < M ? rg : M - 1;
            const float* p = &Af[(size_t)rg * K + k0 + gs * 8];
            float4 u = *(const float4*)p;
            float4 v = *(const float4*)(p + 4);
            u16x8 o;
            o[0] = f2bf(u.x); o[1] = f2bf(u.y); o[2] = f2bf(u.z); o[3] = f2bf(u.w);
            o[4] = f2bf(v.x); o[5] = f2bf(v.y); o[6] = f2bf(v.z); o[7] = f2bf(v.w);
            *(u16x8*)&As[r * 8 + g] = o;
        } else {
            const unsigned short* Ab = (const unsigned short*)Av;
            int glin = w * 64 + lane;            // wave w stages granules [64w,64w+64)
            int r = glin >> 3, g = glin & 7;
            int gs = g ^ (r & 7);
            int rg = bm + r; rg = rg < M ? rg : M - 1;
            gload16(&Ab[(size_t)rg * K + k0 + gs * 8], &As[w * 64]);
        }
        // stage B: 2048 granules via global_load_lds
#pragma unroll
        for (int i = 0; i < 8; ++i) {
            int glin = w * 512 + i * 64 + lane;
            int n = glin >> 3, g = glin & 7;
            int gs = g ^ (n & 7);
            gload16(&BT[(size_t)n * K + k0 + gs * 8], &Bs[w * 512 + i * 64]);
        }
        __syncthreads();  // drains vmcnt + lgkm

        // compute: all 32 rows x wave-private 64 cols
#pragma unroll
        for (int h = 0; h < 2; ++h) {
            int r0 = lr, r1 = 16 + lr;
            bf16x8 a0 = *(const bf16x8*)&As[r0 * 8 + ((4 * h + kg) ^ (r0 & 7))];
            bf16x8 a1 = *(const bf16x8*)&As[r1 * 8 + ((4 * h + kg) ^ (r1 & 7))];
#pragma unroll
            for (int f = 0; f < 4; ++f) {
                int nr = 64 * w + 16 * f + lr;
                bf16x8 bf = *(const bf16x8*)&Bs[nr * 8 + ((4 * h + kg) ^ (nr & 7))];
                acc[0][f] = __builtin_amdgcn_mfma_f32_16x16x32_bf16(bf, a0, acc[0][f], 0, 0, 0);
                acc[1][f] = __builtin_amdgcn_mfma_f32_16x16x32_bf16(bf, a1, acc[1][f], 0, 0, 0);
            }
        }
        __syncthreads();
    }
    // epilogue: swapped layout -> lane lr = out row, col = 64w + 16f + 4kg
#pragma unroll
    for (int m = 0; m < 2; ++m) {
        int orow = bm + 16 * m + lr;
        if (orow < M) {
#pragma unroll
            for (int f = 0; f < 4; ++f) {
                ushort4 o = make_ushort4(f2bf(acc[m][f][0]), f2bf(acc[m][f][1]),
                                         f2bf(acc[m][f][2]), f2bf(acc[m][f][3]));
                *(ushort4*)&C[(size_t)orow * 256 + 64 * w + 16 * f + 4 * kg] = o;
            }
        }
    }
}

// ---------------- CSR aggregation: 16B gathers, 2 edges per wave-step ------
template <bool RELU, bool OUTBF>
__global__ __launch_bounds__(256) void agg_csr(const unsigned short* __restrict__ h,
                                               const float* __restrict__ dinv,
                                               const int* __restrict__ rowstart,
                                               const int* __restrict__ col,
                                               const float* __restrict__ bias,
                                               void* __restrict__ outv) {
    int node = (blockIdx.x * 256 + threadIdx.x) >> 6;
    if (node >= N_NODES) return;
    const int lane = threadIdx.x & 63;
    const int half = lane >> 5, sl = lane & 31;

    float dd = dinv[node];
    float acc[8] = {};

    // self term (half 0 only contributes; half 1 loads same line, weight 0)
    {
        u16x8 hv = *(const u16x8*)&h[(size_t)node * 256 + sl * 8];
        float wgt = half ? 0.f : dd * dd;
#pragma unroll
        for (int i = 0; i < 8; ++i) acc[i] += bf2f(hv[i]) * wgt;
    }

    int j0 = rowstart[node], jend = rowstart[node + 1];
    for (int j = j0; j < jend; j += 2) {
        int sidx = j + half;
        bool p = sidx < jend;
        int s = p ? col[sidx] : node;
        float nrm = p ? dinv[s] * dd : 0.f;
        u16x8 v = *(const u16x8*)&h[(size_t)s * 256 + sl * 8];
#pragma unroll
        for (int i = 0; i < 8; ++i) acc[i] += bf2f(v[i]) * nrm;
    }

    // merge halves
#pragma unroll
    for (int i = 0; i < 8; ++i) acc[i] += __shfl_xor(acc[i], 32);

    if (half == 0) {
        float4 b0 = *(const float4*)&bias[sl * 8];
        float4 b1 = *(const float4*)&bias[sl * 8 + 4];
        acc[0] += b0.x; acc[1] += b0.y; acc[2] += b0.z; acc[3] += b0.w;
        acc[4] += b1.x; acc[5] += b1.y; acc[6] += b1.z; acc[7] += b1.w;
        if (RELU) {
#pragma unroll
            for (int i = 0; i < 8; ++i) acc[i] = fmaxf(acc[i], 0.f);
        }
        if (OUTBF) {
            u16x8 o;
#pragma unroll
            for (int i = 0; i < 8; ++i) o[i] = f2bf(acc[i]);
            *(u16x8*)((unsigned short*)outv + (size_t)node * 256 + sl * 8) = o;
        } else {
            float* ob = (float*)outv + (size_t)node * 256 + sl * 8;
            *(float4*)ob = make_float4(acc[0], acc[1], acc[2], acc[3]);
            *(float4*)(ob + 4) = make_float4(acc[4], acc[5], acc[6], acc[7]);
        }
    }
}

// ---------------- parallel segmented pooling ----------------
#define POOL_CHUNK 49
__global__ __launch_bounds__(256) void pool_partial(const float* __restrict__ x,
                                                    const int* __restrict__ batch,
                                                    float* __restrict__ gsum) {
    int lo = blockIdx.x * POOL_CHUNK;
    if (lo >= N_NODES) return;
    int hi = lo + POOL_CHUNK; if (hi > N_NODES) hi = N_NODES;
    int c = threadIdx.x;
    int g = batch[lo];
    float acc = 0.f;
    for (int n = lo; n < hi; ++n) {
        int gn = batch[n];
        if (gn != g) { atomicAdd(&gsum[g * 256 + c], acc); acc = 0.f; g = gn; }
        acc += x[(size_t)n * 256 + c];
    }
    atomicAdd(&gsum[g * 256 + c], acc);
}

// ---------------- FC head (graph bounds via in-kernel binary search) --------
__global__ __launch_bounds__(256) void fc_head(const float* __restrict__ gsum,
                                               const int* __restrict__ batch,
                                               const float* __restrict__ Wfc,
                                               const float* __restrict__ bfc,
                                               float* __restrict__ out) {
    int g = blockIdx.x;
    int c = threadIdx.x;
    int lo = 0, hi = N_NODES;
    while (lo < hi) { int m = (lo + hi) >> 1; if (batch[m] < g) lo = m + 1; else hi = m; }
    int lo2 = lo, hi2 = N_NODES;
    while (lo2 < hi2) { int m = (lo2 + hi2) >> 1; if (batch[m] < g + 1) lo2 = m + 1; else hi2 = m; }
    float inv = 1.0f / fmaxf((float)(lo2 - lo), 1.0f);
    __shared__ float pooled[256];
    pooled[c] = gsum[(size_t)g * 256 + c] * inv;
    __syncthreads();
    if (c < N_CLASSES) {
        float acc = bfc[c];
        for (int k = 0; k < 256; ++k) acc += pooled[k] * Wfc[k * N_CLASSES + c];
        out[g * N_CLASSES + c] = acc;
    }
}

extern "C" void kernel_launch(void* const* d_in, const int* in_sizes, int n_in,
                              void* d_out, int out_size, void* d_ws, size_t ws_size,
                              hipStream_t stream) {
    const float* emb  = (const float*)d_in[0];
    const int*   eidx = (const int*)d_in[1];
    const int*   batch= (const int*)d_in[2];
    const float* W1   = (const float*)d_in[3];
    const float* b1   = (const float*)d_in[4];
    const float* W2   = (const float*)d_in[5];
    const float* b2   = (const float*)d_in[6];
    const float* Wfc  = (const float*)d_in[7];
    const float* bfc  = (const float*)d_in[8];
    float* out = (float*)d_out;

    const int* src = eidx;
    const int* dst = eidx + N_EDGES;

    char* ws = (char*)d_ws;
    size_t off = 0;
    auto alloc = [&](size_t bytes) { void* p = ws + off; off += (bytes + 1023) & ~(size_t)1023; return p; };
    int*   rowcnt   = (int*)alloc(N_NODES * 4);
    int*   rowstart = (int*)alloc((N_NODES + 1) * 4);
    int*   cursor   = (int*)alloc(N_NODES * 4);
    int*   col      = (int*)alloc(N_EDGES * 4);
    float* dinv     = (float*)alloc(N_NODES * 4);
    float* gsum     = (float*)alloc((size_t)N_GRAPHS * 256 * 4);
    unsigned short* W1T = (unsigned short*)alloc((size_t)HIDDEN * IN_DIM * 2);   // [256][768]
    unsigned short* W2T = (unsigned short*)alloc((size_t)HIDDEN * HIDDEN * 2);   // [256][256]
    unsigned short* bufH = (unsigned short*)alloc((size_t)N_NODES * 256 * 2);    // h (bf16)
    unsigned short* x1 = (unsigned short*)alloc((size_t)N_NODES * 256 * 2);      // bf16
    float* x2 = (float*)alloc((size_t)N_NODES * 256 * 4);                        // f32

    const int NB = (N_NODES + 255) / 256;
    const int EBk = (N_EDGES + 255) / 256;
    const int AGG_B = (N_NODES * 64 + 255) / 256;  // 12500
    dim3 gemm_grid((N_NODES + 31) / 32, 1);        // 1563 blocks, full N per block
    const int POOL_B = (N_NODES + POOL_CHUNK - 1) / POOL_CHUNK;  // 1021

    // CSR + norm
    zero_int<<<NB, 256, 0, stream>>>(rowcnt, N_NODES);
    hist_dst<<<EBk, 256, 0, stream>>>(dst, rowcnt);
    scan_kernel<<<1, 1024, 0, stream>>>(rowcnt, rowstart, cursor, dinv);
    scatter_edges<<<EBk, 256, 0, stream>>>(src, dst, cursor, col);
    zero_f32<<<(N_GRAPHS * 256 + 255) / 256, 256, 0, stream>>>(gsum, N_GRAPHS * 256);

    // weight transposes (bf16)
    transpose_w_bf16<<<dim3(IN_DIM / 32, 8), 256, 0, stream>>>(W1, W1T, IN_DIM);
    transpose_w_bf16<<<dim3(HIDDEN / 32, 8), 256, 0, stream>>>(W2, W2T, HIDDEN);

    // conv1: h1 = emb @ W1 (f32 A converted in-staging), then agg -> x1 (bf16, relu)
    gemm_mfma<IN_DIM, true><<<gemm_grid, 256, 0, stream>>>(emb, W1T, bufH, N_NODES);
    agg_csr<true, true><<<AGG_B, 256, 0, stream>>>(bufH, dinv, rowstart, col, b1, x1);

    // conv2: h2 = x1 @ W2, then agg -> x2 (f32)
    gemm_mfma<HIDDEN, false><<<gemm_grid, 256, 0, stream>>>(x1, W2T, bufH, N_NODES);
    agg_csr<false, false><<<AGG_B, 256, 0, stream>>>(bufH, dinv, rowstart, col, b2, x2);

    // pool + head
    pool_partial<<<POOL_B, 256, 0, stream>>>(x2, batch, gsum);
    fc_head<<<N_GRAPHS, 256, 0, stream>>>(gsum, batch, Wfc, bfc, out);
}